// Round 5
// baseline (87.454 us; speedup 1.0000x reference)
//
#include <hip/hip_runtime.h>
#include <hip/hip_bf16.h>

// out[8192,64] = L[8192,8192] (fp32) @ M[8192,64] (fp32)
// K1: BT[h][k] = (bf16)M[k][h]  (1 MB in d_ws, L2-resident)
// K2: A staged fp32 via global_load_lds(16B), double-buffered, XOR-swizzled
//     (pre-swizzled global source, swizzled ds_read). B fragment-direct from BT,
//     double-buffered in NAMED reg arrays (constant indices only).
//     Counted s_waitcnt vmcnt(12) — next tile's 12 loads stay in flight across
//     both barriers; vmcnt(0) only at the final step. Split-K=8, fp32 atomics.

#define NPED 8192
#define HID  64
#define BM   64
#define BK   64
#define KSPLIT 8
#define KRANGE (NPED / KSPLIT)   // 1024
#define NSTEPS (KRANGE / BK)     // 16

typedef __bf16 bf16x8 __attribute__((ext_vector_type(8)));
typedef float  f32x4  __attribute__((ext_vector_type(4)));
typedef unsigned short u16;
typedef u16 u16x8 __attribute__((ext_vector_type(8)));

__device__ __forceinline__ bf16x8 cvt8(float4 lo, float4 hi) {
    bf16x8 r;
    r[0] = (__bf16)lo.x; r[1] = (__bf16)lo.y; r[2] = (__bf16)lo.z; r[3] = (__bf16)lo.w;
    r[4] = (__bf16)hi.x; r[5] = (__bf16)hi.y; r[6] = (__bf16)hi.z; r[7] = (__bf16)hi.w;
    return r;
}

__device__ __forceinline__ void gl_lds16(const void* g, void* l) {
    __builtin_amdgcn_global_load_lds(
        (const __attribute__((address_space(1))) void*)g,
        (__attribute__((address_space(3))) void*)l, 16, 0, 0);
}

// ---- Kernel 1: B [8192,64] fp32 -> BT [64,8192] bf16 ----
__global__ __launch_bounds__(256)
void transpose_b(const float* __restrict__ B, u16* __restrict__ BT) {
    __shared__ u16 t[64][65];
    const int tid = threadIdx.x;
    const int kb  = blockIdx.x * 64;
    {
        const int r  = tid >> 2;
        const int c0 = (tid & 3) * 16;
        const float* p = B + (long)(kb + r) * HID + c0;
        #pragma unroll
        for (int j = 0; j < 16; j += 4) {
            float4 v = *(const float4*)(p + j);
            __bf16 b0 = (__bf16)v.x, b1 = (__bf16)v.y, b2 = (__bf16)v.z, b3 = (__bf16)v.w;
            t[c0 + j + 0][r] = __builtin_bit_cast(u16, b0);
            t[c0 + j + 1][r] = __builtin_bit_cast(u16, b1);
            t[c0 + j + 2][r] = __builtin_bit_cast(u16, b2);
            t[c0 + j + 3][r] = __builtin_bit_cast(u16, b3);
        }
    }
    __syncthreads();
    {
        const int h  = tid >> 2;
        const int kc = (tid & 3) * 16;
        u16x8 lo, hi;
        #pragma unroll
        for (int j = 0; j < 8; ++j) { lo[j] = t[h][kc + j]; hi[j] = t[h][kc + 8 + j]; }
        u16* q = BT + (long)h * NPED + kb + kc;
        *(u16x8*)(q)     = lo;
        *(u16x8*)(q + 8) = hi;
    }
}

// ---- Kernel 2: streaming MFMA ----
__global__ __launch_bounds__(256, 4)
void crowd_mm(const float* __restrict__ A, const u16* __restrict__ BT,
              float* __restrict__ out)
{
    __shared__ float lds0[BM * BK];   // 16 KB, row-XOR-swizzled fp32 A tile
    __shared__ float lds1[BM * BK];   // 16 KB

    const int tid  = threadIdx.x;
    const int lane = tid & 63;
    const int w    = tid >> 6;
    const int rb   = blockIdx.x;
    const int ks   = blockIdx.y;

    const int l15  = lane & 15;
    const int l4   = lane >> 4;
    const int kb16 = l15 * 16;        // staging: byte col within 256-B row

    // A tile base (bytes): block rows rb*64.., k-slice ks*1024 floats
    const char* Abase = (const char*)(A + (long)(rb * BM) * NPED + (long)ks * KRANGE);
    // B fragments: h = l15 (+16t), k = ks*1024 + step*64 + s*32 + l4*8 + [0..7]
    const u16* Bp = BT + (long)l15 * NPED + (long)ks * KRANGE + l4 * 8;

    u16x8 B0[8], B1[8];               // named double buffers, constant-indexed only
    f32x4 acc[4] = {};

    // stage step STEP of A into LBUF: 4 calls/wave, 1 KB each; lane l -> dest
    // byte (w*4+I)*1024 + l*16 = row (w*16+4I+(l>>4)), col (l&15)*16.
    // Source col pre-XOR'd so LDS[r][x] = A[r][x ^ ((r&7)<<4)].
#define STAGE(LBUF, STEP) do {                                                   \
    _Pragma("unroll")                                                            \
    for (int I = 0; I < 4; ++I) {                                                \
        const int row4 = w * 16 + I * 4 + (lane >> 4);                           \
        const char* src = Abase + (long)row4 * (NPED * 4)                        \
                        + (long)(STEP) * 256 + (kb16 ^ ((row4 & 7) << 4));       \
        gl_lds16(src, (char*)(LBUF) + (w * 4 + I) * 1024);                       \
    }                                                                            \
} while (0)

#define LOADB(DST, STEP) do {                                                    \
    _Pragma("unroll")                                                            \
    for (int t = 0; t < 4; ++t) {                                                \
        const u16* bp = Bp + (long)(STEP) * BK + (long)t * 16 * NPED;            \
        DST[t]     = *(const u16x8*)bp;                                          \
        DST[4 + t] = *(const u16x8*)(bp + 32);                                   \
    }                                                                            \
} while (0)

    // one K-step: counted vmcnt keeps younger loads in flight; two barriers
#define HALF(LBUF, BREG, VM) do {                                                \
    asm volatile("s_waitcnt vmcnt(" #VM ")" ::: "memory");                       \
    __builtin_amdgcn_s_barrier();                                                \
    const char* base_ = (const char*)(LBUF);                                     \
    const int row_   = w * 16 + l15;                                             \
    const int sw_    = (row_ & 7) << 4;                                          \
    const int rbyte_ = row_ * 256;                                               \
    float4 fa0 = *(const float4*)(base_ + rbyte_ + ((l4 * 32)            ^ sw_));\
    float4 fa1 = *(const float4*)(base_ + rbyte_ + ((l4 * 32 + 16)       ^ sw_));\
    float4 fa2 = *(const float4*)(base_ + rbyte_ + ((128 + l4 * 32)      ^ sw_));\
    float4 fa3 = *(const float4*)(base_ + rbyte_ + ((128 + l4 * 32 + 16) ^ sw_));\
    asm volatile("s_waitcnt lgkmcnt(0)" ::: "memory");                           \
    __builtin_amdgcn_s_barrier();                                                \
    bf16x8 af0 = cvt8(fa0, fa1);                                                 \
    bf16x8 af1 = cvt8(fa2, fa3);                                                 \
    _Pragma("unroll")                                                            \
    for (int t = 0; t < 4; ++t)                                                  \
        acc[t] = __builtin_amdgcn_mfma_f32_16x16x32_bf16(                        \
            af0, __builtin_bit_cast(bf16x8, BREG[t]), acc[t], 0, 0, 0);          \
    _Pragma("unroll")                                                            \
    for (int t = 0; t < 4; ++t)                                                  \
        acc[t] = __builtin_amdgcn_mfma_f32_16x16x32_bf16(                        \
            af1, __builtin_bit_cast(bf16x8, BREG[4 + t]), acc[t], 0, 0, 0);      \
} while (0)

    // Prologue: two tiles in flight (issue order: B(s) before A(s))
    LOADB(B0, 0);
    STAGE(lds0, 0);
    LOADB(B1, 1);
    STAGE(lds1, 1);

    for (int it = 0; it < 7; ++it) {
        const int s0 = 2 * it;
        HALF(lds0, B0, 12);            // consume step s0
        LOADB(B0, s0 + 2);
        STAGE(lds0, s0 + 2);
        HALF(lds1, B1, 12);            // consume step s0+1
        LOADB(B1, s0 + 3);
        STAGE(lds1, s0 + 3);
    }
    HALF(lds0, B0, 12);                // s = 14 (keeps step-15 loads in flight)
    HALF(lds1, B1, 0);                 // s = 15 (final drain)

    // Epilogue: C/D layout col = lane&15, row = (lane>>4)*4 + reg
    #pragma unroll
    for (int t = 0; t < 4; ++t) {
        #pragma unroll
        for (int r = 0; r < 4; ++r) {
            int row = rb * BM + w * 16 + l4 * 4 + r;
            int col = t * 16 + l15;
            atomicAdd(&out[row * HID + col], acc[t][r]);
        }
    }
#undef STAGE
#undef LOADB
#undef HALF
}

extern "C" void kernel_launch(void* const* d_in, const int* in_sizes, int n_in,
                              void* d_out, int out_size, void* d_ws, size_t ws_size,
                              hipStream_t stream) {
    const float* A = (const float*)d_in[0];   // location_data [8192, 8192]
    const float* B = (const float*)d_in[1];   // motion_data   [8192, 64]
    float* out = (float*)d_out;               // [8192, 64]
    u16* BT = (u16*)d_ws;                     // 64*8192*2 = 1 MB scratch

    hipMemsetAsync(d_out, 0, (size_t)out_size * sizeof(float), stream);
    transpose_b<<<dim3(NPED / 64), 256, 0, stream>>>(B, BT);

    dim3 grid(NPED / BM, KSPLIT);
    crowd_mm<<<grid, 256, 0, stream>>>(A, BT, out);
}

// Round 6
// 57.578 us; speedup vs baseline: 1.5189x; 1.5189x over previous
//
#include <hip/hip_runtime.h>
#include <hip/hip_bf16.h>

// out[8192,64] = L[8192,8192] (fp32) @ M[8192,64] (fp32)
// K1 (build_btf): BTF = B as bf16 in MFMA-fragment order: for each kstep S
//     (64 k's), 8 fragments f=(s*4+t), each 64 lanes x 16B contiguous (8KB/S).
// K2 (crowd_mm): BM=128, 512 thr (8 waves), 2 blocks/CU (LDS 80KB).
//     A: global_load_lds fp32, XOR-swizzled (pre-swizzled source), dbuf 2x32KB.
//     B: ONE contiguous 1KB global_load_lds per wave/step into dbuf 2x8KB LDS,
//        read back as contiguous ds_read_b128 (conflict-free, zero VGPR bufs).
//     Counted s_waitcnt vmcnt(5) (next step's 5 loads stay in flight), drain
//     only at final step. Split-K=8, fp32 atomics onto memset-zeroed out.

#define NPED 8192
#define HID  64
#define BM   128
#define BK   64
#define KSPLIT 8
#define KRANGE (NPED / KSPLIT)   // 1024
#define NSTEPS (KRANGE / BK)     // 16

typedef __bf16 bf16x8 __attribute__((ext_vector_type(8)));
typedef float  f32x4  __attribute__((ext_vector_type(4)));
typedef unsigned short u16;
typedef u16 u16x8 __attribute__((ext_vector_type(8)));

__device__ __forceinline__ bf16x8 cvt8(float4 lo, float4 hi) {
    bf16x8 r;
    r[0] = (__bf16)lo.x; r[1] = (__bf16)lo.y; r[2] = (__bf16)lo.z; r[3] = (__bf16)lo.w;
    r[4] = (__bf16)hi.x; r[5] = (__bf16)hi.y; r[6] = (__bf16)hi.z; r[7] = (__bf16)hi.w;
    return r;
}

__device__ __forceinline__ void gl_lds16(const void* g, void* l) {
    __builtin_amdgcn_global_load_lds(
        (const __attribute__((address_space(1))) void*)g,
        (__attribute__((address_space(3))) void*)l, 16, 0, 0);
}

// ---- K1: B [8192,64] fp32 -> BTF fragment-ordered bf16 (1 MB) ----
// BTF element ((S*8+f)*64 + l)*8 + j = bf16(B[S*64 + s*32 + (l>>4)*8 + j][t*16 + (l&15)])
// with s = f>>2, t = f&3.
__global__ __launch_bounds__(256)
void build_btf(const float* __restrict__ B, u16* __restrict__ BTF) {
    __shared__ u16 t[64][72];            // [h][k-local], 16B-aligned rows
    const int tid = threadIdx.x;
    const int S   = blockIdx.x;          // kstep 0..127
    const int kb  = S * 64;
    {
        const int r  = tid >> 2;         // k-local
        const int c0 = (tid & 3) * 16;   // h base
        const float* p = B + (long)(kb + r) * HID + c0;
        #pragma unroll
        for (int j = 0; j < 16; j += 4) {
            float4 v = *(const float4*)(p + j);
            __bf16 b0 = (__bf16)v.x, b1 = (__bf16)v.y, b2 = (__bf16)v.z, b3 = (__bf16)v.w;
            t[c0 + j + 0][r] = __builtin_bit_cast(u16, b0);
            t[c0 + j + 1][r] = __builtin_bit_cast(u16, b1);
            t[c0 + j + 2][r] = __builtin_bit_cast(u16, b2);
            t[c0 + j + 3][r] = __builtin_bit_cast(u16, b3);
        }
    }
    __syncthreads();
    {
        const int f  = tid >> 5;              // fragment 0..7
        const int s  = f >> 2, tt = f & 3;
        const int l0 = (tid & 31) * 2;        // two lanes per thread
        u16* q = BTF + ((long)(S * 8 + f) * 64 + l0) * 8;
        #pragma unroll
        for (int i = 0; i < 2; ++i) {
            const int l  = l0 + i;
            const int h  = tt * 16 + (l & 15);
            const int kl = s * 32 + (l >> 4) * 8;
            u16x8 v;
            #pragma unroll
            for (int j = 0; j < 8; ++j) v[j] = t[h][kl + j];
            *(u16x8*)(q + i * 8) = v;
        }
    }
}

// ---- K2: streaming MFMA ----
__global__ __launch_bounds__(512, 4)
void crowd_mm(const float* __restrict__ A, const u16* __restrict__ BTF,
              float* __restrict__ out)
{
    __shared__ float Aa[BM * BK];   // 32 KB, row-XOR-swizzled fp32 A tile
    __shared__ float Ab[BM * BK];   // 32 KB
    __shared__ u16   Ba[4096];      // 8 KB, fragment-ordered bf16 B tile
    __shared__ u16   Bb[4096];      // 8 KB

    const int tid  = threadIdx.x;
    const int lane = tid & 63;
    const int w    = tid >> 6;       // wave 0..7, owns rows w*16..+15
    const int rb   = blockIdx.x;     // 0..63
    const int ks   = blockIdx.y;     // 0..7

    const int l15  = lane & 15;
    const int l4   = lane >> 4;
    const int cb16 = l15 * 16;       // A staging col byte within 256-B row

    // A tile: rows rb*128.., k-slice ks*1024
    const char* Abase = (const char*)(A + (long)(rb * BM) * NPED + (long)ks * KRANGE);
    // B fragments: chunk (S*8 + w), per-lane 16B; S = ks*16 + step
    const u16* Bbase = BTF + ((long)(ks * NSTEPS) * 8 + w) * 512 + lane * 8;

    f32x4 acc[4] = {};

    // per wave per step: 1 B-stage + 4 A-stage global_load_lds (5 vmem)
#define STAGE(ALDS, BLDS, STEP) do {                                             \
    gl_lds16(Bbase + (long)(STEP) * (8 * 512), (char*)(BLDS) + w * 1024);        \
    _Pragma("unroll")                                                            \
    for (int I = 0; I < 4; ++I) {                                                \
        const int row4 = w * 16 + I * 4 + l4;                                    \
        const char* src = Abase + (long)row4 * (NPED * 4)                        \
                        + (long)(STEP) * 256 + (cb16 ^ ((row4 & 7) << 4));       \
        gl_lds16(src, (char*)(ALDS) + (w * 4 + I) * 1024);                       \
    }                                                                            \
} while (0)

#define HALF(ALDS, BLDS, VM) do {                                                \
    asm volatile("s_waitcnt vmcnt(" #VM ")" ::: "memory");                       \
    __builtin_amdgcn_s_barrier();                                                \
    const char* ab_ = (const char*)(ALDS);                                       \
    const char* bb_ = (const char*)(BLDS);                                       \
    const int row_ = w * 16 + l15;                                               \
    const int sw_  = (row_ & 7) << 4;                                            \
    const int rB_  = row_ * 256;                                                 \
    float4 fa0 = *(const float4*)(ab_ + rB_ + ((l4 * 32)            ^ sw_));     \
    float4 fa1 = *(const float4*)(ab_ + rB_ + ((l4 * 32 + 16)       ^ sw_));     \
    float4 fa2 = *(const float4*)(ab_ + rB_ + ((128 + l4 * 32)      ^ sw_));     \
    float4 fa3 = *(const float4*)(ab_ + rB_ + ((128 + l4 * 32 + 16) ^ sw_));     \
    bf16x8 bf0 = *(const bf16x8*)(bb_ + 0 * 1024 + lane * 16);                   \
    bf16x8 bf1 = *(const bf16x8*)(bb_ + 1 * 1024 + lane * 16);                   \
    bf16x8 bf2 = *(const bf16x8*)(bb_ + 2 * 1024 + lane * 16);                   \
    bf16x8 bf3 = *(const bf16x8*)(bb_ + 3 * 1024 + lane * 16);                   \
    bf16x8 bf4 = *(const bf16x8*)(bb_ + 4 * 1024 + lane * 16);                   \
    bf16x8 bf5 = *(const bf16x8*)(bb_ + 5 * 1024 + lane * 16);                   \
    bf16x8 bf6 = *(const bf16x8*)(bb_ + 6 * 1024 + lane * 16);                   \
    bf16x8 bf7 = *(const bf16x8*)(bb_ + 7 * 1024 + lane * 16);                   \
    asm volatile("s_waitcnt lgkmcnt(0)" ::: "memory");                           \
    __builtin_amdgcn_s_barrier();                                                \
    bf16x8 af0 = cvt8(fa0, fa1);                                                 \
    bf16x8 af1 = cvt8(fa2, fa3);                                                 \
    acc[0] = __builtin_amdgcn_mfma_f32_16x16x32_bf16(af0, bf0, acc[0], 0, 0, 0); \
    acc[1] = __builtin_amdgcn_mfma_f32_16x16x32_bf16(af0, bf1, acc[1], 0, 0, 0); \
    acc[2] = __builtin_amdgcn_mfma_f32_16x16x32_bf16(af0, bf2, acc[2], 0, 0, 0); \
    acc[3] = __builtin_amdgcn_mfma_f32_16x16x32_bf16(af0, bf3, acc[3], 0, 0, 0); \
    acc[0] = __builtin_amdgcn_mfma_f32_16x16x32_bf16(af1, bf4, acc[0], 0, 0, 0); \
    acc[1] = __builtin_amdgcn_mfma_f32_16x16x32_bf16(af1, bf5, acc[1], 0, 0, 0); \
    acc[2] = __builtin_amdgcn_mfma_f32_16x16x32_bf16(af1, bf6, acc[2], 0, 0, 0); \
    acc[3] = __builtin_amdgcn_mfma_f32_16x16x32_bf16(af1, bf7, acc[3], 0, 0, 0); \
} while (0)

    // Prologue: two steps in flight (10 vmem outstanding per wave)
    STAGE(Aa, Ba, 0);
    STAGE(Ab, Bb, 1);

    #pragma unroll
    for (int it = 0; it < 7; ++it) {
        HALF(Aa, Ba, 5);               // consume step 2*it   (step 2*it+1 in flight)
        STAGE(Aa, Ba, 2 * it + 2);
        HALF(Ab, Bb, 5);               // consume step 2*it+1
        STAGE(Ab, Bb, 2 * it + 3);
    }
    HALF(Aa, Ba, 5);                   // step 14 (step 15 stays in flight)
    HALF(Ab, Bb, 0);                   // step 15 (final drain)

    // Epilogue: C/D layout col = lane&15, row = (lane>>4)*4 + reg
    #pragma unroll
    for (int t = 0; t < 4; ++t) {
        #pragma unroll
        for (int r = 0; r < 4; ++r) {
            int row = rb * BM + w * 16 + l4 * 4 + r;
            int col = t * 16 + l15;
            atomicAdd(&out[row * HID + col], acc[t][r]);
        }
    }
#undef STAGE
#undef HALF
}

extern "C" void kernel_launch(void* const* d_in, const int* in_sizes, int n_in,
                              void* d_out, int out_size, void* d_ws, size_t ws_size,
                              hipStream_t stream) {
    const float* A = (const float*)d_in[0];   // location_data [8192, 8192]
    const float* B = (const float*)d_in[1];   // motion_data   [8192, 64]
    float* out = (float*)d_out;               // [8192, 64]
    u16* BTF = (u16*)d_ws;                    // 1 MB fragment-ordered B

    hipMemsetAsync(d_out, 0, (size_t)out_size * sizeof(float), stream);
    build_btf<<<dim3(NPED / 64), 256, 0, stream>>>(B, BTF);

    dim3 grid(NPED / BM, KSPLIT);
    crowd_mm<<<grid, 512, 0, stream>>>(A, BTF, out);
}